// Round 5
// baseline (205.014 us; speedup 1.0000x reference)
//
#include <hip/hip_runtime.h>

// R9 == R8 resubmitted byte-identical (R8 bench was an infra failure:
// "MI355X container failed twice" — no compile/correctness verdict; same
// failure mode in R2 resolved by byte-identical resubmission in R3).

#define NPTS  64
#define NANG  2016          // 64*63/2
#define NCOLS 300000
#define NTILE (NCOLS / 16)  // 18750 16-column wave tiles (300000 % 16 == 0)

typedef float v4 __attribute__((ext_vector_type(4)));
typedef __attribute__((ext_vector_type(4))) float f32x4;
typedef __attribute__((ext_vector_type(8))) short short8;

#define PSTR 68             // LDS row stride in floats: 16B-aligned (68*4=272=17*16)

// ---------------------------------------------------------------------------
// Kernel 1: build R, then emit A = diag(mus)@R as TWO bf16 MFMA A-fragment
// tables (hi/lo truncation split) into d_ws:
//   tab[((sp*4 + rt)*2 + ks)*512 + l*8 + j]  (ushort bf16 bits)
// holding A[16*rt + (l&15)][32*ks + 8*(l>>4) + j], sp=0: bf16_trunc(A),
// sp=1: bf16_trunc(A - hi). Each lane's 8 bf16 are contiguous (16 B) ->
// ortho_apply loads its v_mfma_f32_16x16x32_bf16 A-fragment with one dwordx4.
// Core build (R6 segmented structure) unchanged; R8 delta = epilogue + the
// scalar-temp sincos guard (defeats any by-pointer array demotion to scratch).
// ---------------------------------------------------------------------------

__device__ __forceinline__ float rl(float x, int lane) {
    return __uint_as_float(__builtin_amdgcn_readlane(__float_as_uint(x), lane));
}

// Groups T..TB-1, exact length 63-T each. S[j] = running[row T+j][col lane].
// Rotation i (1-based) of group T: rows (T, T+i); lane i-1 holds its (c,s).
template<int T, int TB, int TA, int NG>
__device__ __forceinline__ void groups_run(float (&S)[NPTS],
                                           const float (&c)[NG], const float (&s)[NG],
                                           float* __restrict__ slab, int lane)
{
    if constexpr (T < TB) {
        constexpr int g   = T - TA;
        constexpr int LEN = 63 - T;                   // real rotations in group T
        float rt = S[0];
        #pragma unroll
        for (int i = 1; i <= LEN; ++i) {              // compile-time i
            const float cc = rl(c[g], i - 1);         // v_readlane, imm lane
            const float ss = rl(s[g], i - 1);
            const float rb = S[i];
            S[i - 1] = fmaf(ss, rt, cc * rb);         // new row (T+i), pre-shifted
            rt       = fmaf(cc, rt, -ss * rb);        // serial chain
        }
        slab[T * PSTR + lane] = rt;                   // row T of Mw finished
        groups_run<T + 1, TB, TA, NG>(S, c, s, slab, lane);
    }
}

template<int TA, int TB>
__device__ __forceinline__ void do_wave(const float* __restrict__ angles,
                                        float* __restrict__ slab, int lane)
{
    constexpr int NG = TB - TA;
    float c[NG], s[NG];
    #pragma unroll
    for (int g = 0; g < NG; ++g) {                    // all independent -> pipelined
        const int t    = TA + g;
        const int base = 63 * t - (t * (t - 1)) / 2;  // angle base of group t
        float a = 0.0f;
        if (lane < 63 - t) a = angles[base + lane];   // lane i-1 <-> rotation i
        float sv, cv;
        sincosf(a, &sv, &cv);                         // scalar temps: outputs stay
        s[g] = sv; c[g] = cv;                         // promotable to registers
    }

    // segment starts from identity restricted to rows TA..TA+63 (cols<TA: all 0)
    float S[NPTS];
    #pragma unroll
    for (int j = 0; j < NPTS; ++j) S[j] = (TA + j == lane) ? 1.0f : 0.0f;

    groups_run<TA, TB, TA, NG>(S, c, s, slab, lane);

    // rows TB..63 of Mw still live in S[0..63-TB]
    #pragma unroll
    for (int j = 0; j <= 63 - TB; ++j)
        slab[(TB + j) * PSTR + lane] = S[j];
}

// P[rows >= RS] = Ms[RS: , RS:] @ P[RS: , :]; rows < RS of P unchanged.
// k4 starts at RS/4: Ms cols < RS are exact zeros, so partial quads are safe.
template<int RS>
__device__ __forceinline__ void combine_step(float* __restrict__ P,
                                             const float* __restrict__ Ms,
                                             int tid)
{
    const int c4 = tid & 15;                          // v4 column 0..15
    const int rg = tid >> 4;                          // row group 0..15
    constexpr int NR   = 64 - RS;
    constexpr int NIT  = (NR + 15) / 16;
    constexpr int K4_0 = RS / 4;

    v4 acc[NIT];
    #pragma unroll
    for (int it = 0; it < NIT; ++it) acc[it] = (v4)0.0f;

    #pragma unroll 2
    for (int k4 = K4_0; k4 < 16; ++k4) {
        v4 pv[4];
        #pragma unroll
        for (int j = 0; j < 4; ++j)                   // same addr across lanes-of-16:
            pv[j] = *(const v4*)(P + (4 * k4 + j) * PSTR + 4 * c4);   // broadcast
        #pragma unroll
        for (int it = 0; it < NIT; ++it) {
            const int r = RS + rg + 16 * it;
            if (r < 64) {
                const v4 mv = *(const v4*)(Ms + r * PSTR + 4 * k4);
                acc[it] += pv[0] * mv.x;
                acc[it] += pv[1] * mv.y;
                acc[it] += pv[2] * mv.z;
                acc[it] += pv[3] * mv.w;
            }
        }
    }
    __syncthreads();                                  // all reads of P done
    #pragma unroll
    for (int it = 0; it < NIT; ++it) {
        const int r = RS + rg + 16 * it;
        if (r < 64) *(v4*)(P + r * PSTR + 4 * c4) = acc[it];
    }
    __syncthreads();
}

__global__ __launch_bounds__(256, 1) void ortho_build_R(
    const float* __restrict__ angles, const float* __restrict__ mus,
    unsigned short* __restrict__ tab)
{
    __shared__ float P[NPTS * PSTR];                  // M0, then running product
    __shared__ float M[3][NPTS * PSTR];               // M1, M2, M3 slabs

    const int tid  = threadIdx.x;
    const int lane = tid & 63;
    const int wv   = tid >> 6;

    if      (wv == 0) do_wave< 0,  9>(angles, P,    lane);   // 531 rotations
    else if (wv == 1) do_wave< 9, 19>(angles, M[0], lane);   // 495
    else if (wv == 2) do_wave<19, 32>(angles, M[1], lane);   // 494
    else              do_wave<32, 63>(angles, M[2], lane);   // 496
    __syncthreads();

    combine_step< 9>(P, M[0], tid);                   // P <- M1 @ P (rows 9..63)
    combine_step<19>(P, M[1], tid);                   // P <- M2 @ P (rows 19..63)
    combine_step<32>(P, M[2], tid);                   // P <- M3 @ P (rows 32..63)

    // Epilogue: bf16 hi/lo A-fragment tables. e = rt(2b) ks(1b) l(6b) j(3b).
    // val = mus[row]*R[row][k]; hi = trunc-bf16(val); lo = trunc-bf16(val-hi)
    // (val - hi is EXACT in fp32 -> total split error <= 2^-16 |val|).
    #pragma unroll
    for (int it = 0; it < 16; ++it) {
        const int e  = it * 256 + tid;                // 0..4095
        const int j  = e & 7;
        const int l  = (e >> 3) & 63;
        const int ks = (e >> 9) & 1;
        const int rt = (e >> 10) & 3;
        const int row = 16 * rt + (l & 15);
        const int k   = 32 * ks + 8 * (l >> 4) + j;
        const float val = mus[row] * P[row * PSTR + k];
        const unsigned u  = __float_as_uint(val);
        const float    d  = val - __uint_as_float(u & 0xffff0000u);
        tab[e]        = (unsigned short)(u >> 16);
        tab[4096 + e] = (unsigned short)(__float_as_uint(d) >> 16);
    }
}

// ---------------------------------------------------------------------------
// Kernel 2 (R8 rewrite): Y = A @ X via v_mfma_f32_16x16x32_bf16, 3-term
// bf16 split: Y = a1@x1 + a1@x2 + a2@x1 (fp32 accumulate).
// One wave per 16-column tile, all 64 rows (4 row-tiles), K=64 = 2 k-steps.
// A fragments: 16 dwordx4 loads (L1/L2-resident 16 KB table, same layout for
// every wave). X fragments loaded directly in B-layout (lane l: col=l&15,
// k = 8*(l>>4)+j) -- coalesced dword loads, split to bf16 in-register, no LDS.
// C/D layout (HW-verified m89): col = lane&15, row = 4*(lane>>4) + reg.
// Any consistent k-permutation between the A table and the B fill cancels in
// the dot product, so only the M/N lane mapping must be absolutely correct.
// Split error <= ~2e-3 absolute, well under the 0.015625 tolerance.
// ---------------------------------------------------------------------------
__global__ __launch_bounds__(256) void ortho_apply(
    const float* __restrict__ X, const unsigned short* __restrict__ tab,
    float* __restrict__ Y)
{
    const int l    = threadIdx.x & 63;
    const int wv   = threadIdx.x >> 6;
    const int tile = blockIdx.x * 4 + wv;
    if (tile >= NTILE) return;                        // wave-uniform exit, no barriers
    const int col = tile * 16 + (l & 15);
    const int g   = l >> 4;                           // k-group 0..3

    // A fragments [split][rt][ks]; each lane's 8 bf16 contiguous -> dwordx4
    const short8* At = (const short8*)tab;
    short8 a[2][4][2];
    #pragma unroll
    for (int sp = 0; sp < 2; ++sp)
        #pragma unroll
        for (int rt = 0; rt < 4; ++rt)
            #pragma unroll
            for (int ks = 0; ks < 2; ++ks)
                a[sp][rt][ks] = At[((sp * 4 + rt) * 2 + ks) * 64 + l];

    f32x4 acc[4];
    #pragma unroll
    for (int rt = 0; rt < 4; ++rt) acc[rt] = (f32x4)0.0f;

    const float* px = X + (size_t)(8 * g) * NCOLS + col;   // k = 32ks + 8g + j

    #pragma unroll
    for (int ks = 0; ks < 2; ++ks) {
        float xv[8];
        #pragma unroll
        for (int j = 0; j < 8; ++j)
            xv[j] = px[(size_t)(32 * ks + j) * NCOLS];

        short8 b1, b2;                                 // hi / lo bf16 of X
        #pragma unroll
        for (int j = 0; j < 8; ++j) {
            const unsigned u = __float_as_uint(xv[j]);
            b1[j] = (short)(u >> 16);                  // trunc bf16
            const float d = xv[j] - __uint_as_float(u & 0xffff0000u);  // exact
            b2[j] = (short)(__float_as_uint(d) >> 16);
        }

        #pragma unroll
        for (int rt = 0; rt < 4; ++rt) {
            acc[rt] = __builtin_amdgcn_mfma_f32_16x16x32_bf16(a[0][rt][ks], b1, acc[rt], 0, 0, 0);
            acc[rt] = __builtin_amdgcn_mfma_f32_16x16x32_bf16(a[0][rt][ks], b2, acc[rt], 0, 0, 0);
            acc[rt] = __builtin_amdgcn_mfma_f32_16x16x32_bf16(a[1][rt][ks], b1, acc[rt], 0, 0, 0);
        }
    }

    #pragma unroll
    for (int rt = 0; rt < 4; ++rt)
        #pragma unroll
        for (int r = 0; r < 4; ++r) {
            const int row = 16 * rt + 4 * g + r;       // verified C/D mapping
            __builtin_nontemporal_store(acc[rt][r], Y + (size_t)row * NCOLS + col);
        }
}

// ---------------------------------------------------------------------------
extern "C" void kernel_launch(void* const* d_in, const int* in_sizes, int n_in,
                              void* d_out, int out_size, void* d_ws, size_t ws_size,
                              hipStream_t stream) {
    const float* X      = (const float*)d_in[0];   // 64 x 300000
    const float* angles = (const float*)d_in[1];   // 2016
    const float* mus    = (const float*)d_in[2];   // 64
    float* Y = (float*)d_out;                      // 64 x 300000
    unsigned short* tab = (unsigned short*)d_ws;   // 2 x 4096 bf16 = 16 KB

    ortho_build_R<<<1, 256, 0, stream>>>(angles, mus, tab);

    const int nblk = (NTILE + 3) / 4;              // 4688 blocks x 4 wave-tiles
    ortho_apply<<<nblk, 256, 0, stream>>>(X, tab, Y);
}